// Round 3
// baseline (406.082 us; speedup 1.0000x reference)
//
#include <hip/hip_runtime.h>

typedef unsigned long long u64;

#define CDIM 128
#define NC   8388608

// ws layout (float offsets):
//   nrm      @ 0       (960 floats)
//   DT       @ 1024    (122880 floats: DT0@+0 [64x128], DT1@+8192 [128x128],
//                       DT2@+24576 [256x128], DT3@+57344 [512x128])
//   keys     @ 131072  (262144 u64 = 2 MB)   [byte 524288 .. 2621440)
//   partials @ 655360  (32768 floats)        [byte 2621440 .. 2752512)
// total ws needed ~2.63 MB

__device__ __forceinline__ unsigned sortable_f32(float f) {
  unsigned u = __float_as_uint(f);
  return (u & 0x80000000u) ? ~u : (u | 0x80000000u);
}

// ---- kernel 0: column norms + transposed dict copies ----
__global__ void vq_prep(const float* __restrict__ D0, const float* __restrict__ D1,
                        const float* __restrict__ D2, const float* __restrict__ D3,
                        float* __restrict__ nrm, float* __restrict__ DT) {
  int g = blockIdx.x * 256 + threadIdx.x;
  if (g >= 960) return;
  const float* D; int K, k; float* T;
  if (g < 64)       { D = D0; K = 64;  k = g;       T = DT; }
  else if (g < 192) { D = D1; K = 128; k = g - 64;  T = DT + 8192; }
  else if (g < 448) { D = D2; K = 256; k = g - 192; T = DT + 24576; }
  else              { D = D3; K = 512; k = g - 448; T = DT + 57344; }
  float s = 0.f;
  for (int c = 0; c < 128; ++c) {
    float v = D[c * K + k];
    s = fmaf(v, v, s);
    T[k * 128 + c] = v;
  }
  nrm[g] = s;
}

// ---- kernel 1: init argmin keys ----
__global__ void vq_initkeys(u64* __restrict__ keys) {
  int i = blockIdx.x * 256 + threadIdx.x;   // 65536 threads
  #pragma unroll
  for (int j = 0; j < 4; ++j) keys[i * 4 + j] = ~0ull;
}

// ---- kernel 2: score tiles + deterministic atomic argmin ----
// grid = 15 tiles x 256 slabs (b%256 = slab -> all tiles of a slab on one XCD).
// block = 256 thr = 4 waves; wave owns 16 cols; lane owns 4 rows (l, l+64, l+128, l+192).
__global__ __launch_bounds__(256, 4) void vq_tiles(
    const float* __restrict__ x,
    const float* __restrict__ D0, const float* __restrict__ D1,
    const float* __restrict__ D2, const float* __restrict__ D3,
    const float* __restrict__ nrm, u64* __restrict__ keys)
{
  __shared__ float2 cand[4][4][64];   // [wid][rowq][lane] : (crit, col)

  const int b = blockIdx.x;
  const int slab = b & 255;
  const int tile = b >> 8;            // 0..14
  const int t = threadIdx.x;
  const int l = t & 63;
  const int wid = t >> 6;

  const float* D; int K, tb, dict, noff;
  if (tile == 0)      { D = D0; K = 64;  tb = 0;             dict = 0; noff = 0; }
  else if (tile < 3)  { D = D1; K = 128; tb = (tile-1)*64;   dict = 1; noff = 64; }
  else if (tile < 7)  { D = D2; K = 256; tb = (tile-3)*64;   dict = 2; noff = 192; }
  else                { D = D3; K = 512; tb = (tile-7)*64;   dict = 3; noff = 448; }

  const int colbase = tb + wid * 16;
  const int cbu = __builtin_amdgcn_readfirstlane(colbase);
  const float* __restrict__ Dp = D + cbu;

  const int rowbase = slab * 256;
  const float* __restrict__ xr0 = x + (size_t)(rowbase + l) * CDIM;
  const float* __restrict__ xr1 = xr0 + 64 * CDIM;
  const float* __restrict__ xr2 = xr0 + 128 * CDIM;
  const float* __restrict__ xr3 = xr0 + 192 * CDIM;

  float4 acc[4][4];
  #pragma unroll
  for (int q = 0; q < 4; ++q)
    #pragma unroll
    for (int j = 0; j < 4; ++j)
      acc[q][j] = make_float4(0.f, 0.f, 0.f, 0.f);

  #pragma unroll 2
  for (int c4 = 0; c4 < 32; ++c4) {
    float4 xv0 = *(const float4*)(xr0 + c4 * 4);
    float4 xv1 = *(const float4*)(xr1 + c4 * 4);
    float4 xv2 = *(const float4*)(xr2 + c4 * 4);
    float4 xv3 = *(const float4*)(xr3 + c4 * 4);
    #pragma unroll
    for (int cc = 0; cc < 4; ++cc) {
      const float* dr = Dp + (size_t)(c4 * 4 + cc) * K;
      float4 dv0 = *(const float4*)(dr);
      float4 dv1 = *(const float4*)(dr + 4);
      float4 dv2 = *(const float4*)(dr + 8);
      float4 dv3 = *(const float4*)(dr + 12);
      #pragma unroll
      for (int q = 0; q < 4; ++q) {
        float xc = (cc == 0) ? ((q==0)?xv0.x:(q==1)?xv1.x:(q==2)?xv2.x:xv3.x)
                 : (cc == 1) ? ((q==0)?xv0.y:(q==1)?xv1.y:(q==2)?xv2.y:xv3.y)
                 : (cc == 2) ? ((q==0)?xv0.z:(q==1)?xv1.z:(q==2)?xv2.z:xv3.z)
                             : ((q==0)?xv0.w:(q==1)?xv1.w:(q==2)?xv2.w:xv3.w);
        acc[q][0].x = fmaf(xc, dv0.x, acc[q][0].x);
        acc[q][0].y = fmaf(xc, dv0.y, acc[q][0].y);
        acc[q][0].z = fmaf(xc, dv0.z, acc[q][0].z);
        acc[q][0].w = fmaf(xc, dv0.w, acc[q][0].w);
        acc[q][1].x = fmaf(xc, dv1.x, acc[q][1].x);
        acc[q][1].y = fmaf(xc, dv1.y, acc[q][1].y);
        acc[q][1].z = fmaf(xc, dv1.z, acc[q][1].z);
        acc[q][1].w = fmaf(xc, dv1.w, acc[q][1].w);
        acc[q][2].x = fmaf(xc, dv2.x, acc[q][2].x);
        acc[q][2].y = fmaf(xc, dv2.y, acc[q][2].y);
        acc[q][2].z = fmaf(xc, dv2.z, acc[q][2].z);
        acc[q][2].w = fmaf(xc, dv2.w, acc[q][2].w);
        acc[q][3].x = fmaf(xc, dv3.x, acc[q][3].x);
        acc[q][3].y = fmaf(xc, dv3.y, acc[q][3].y);
        acc[q][3].z = fmaf(xc, dv3.z, acc[q][3].z);
        acc[q][3].w = fmaf(xc, dv3.w, acc[q][3].w);
      }
    }
  }

  const float* ns = nrm + noff + cbu;
  float4 nv0 = *(const float4*)(ns);
  float4 nv1 = *(const float4*)(ns + 4);
  float4 nv2 = *(const float4*)(ns + 8);
  float4 nv3 = *(const float4*)(ns + 12);

  #pragma unroll
  for (int q = 0; q < 4; ++q) {
    float best = 1e30f; int bc = 0;
    float cr;
    #define UPD1(AV, NV, OFF) cr = fmaf(-2.f, (AV), (NV)); \
      if (cr < best) { best = cr; bc = colbase + (OFF); }
    UPD1(acc[q][0].x, nv0.x, 0)  UPD1(acc[q][0].y, nv0.y, 1)
    UPD1(acc[q][0].z, nv0.z, 2)  UPD1(acc[q][0].w, nv0.w, 3)
    UPD1(acc[q][1].x, nv1.x, 4)  UPD1(acc[q][1].y, nv1.y, 5)
    UPD1(acc[q][1].z, nv1.z, 6)  UPD1(acc[q][1].w, nv1.w, 7)
    UPD1(acc[q][2].x, nv2.x, 8)  UPD1(acc[q][2].y, nv2.y, 9)
    UPD1(acc[q][2].z, nv2.z, 10) UPD1(acc[q][2].w, nv2.w, 11)
    UPD1(acc[q][3].x, nv3.x, 12) UPD1(acc[q][3].y, nv3.y, 13)
    UPD1(acc[q][3].z, nv3.z, 14) UPD1(acc[q][3].w, nv3.w, 15)
    #undef UPD1
    cand[wid][q][l] = make_float2(best, __int_as_float(bc));
  }
  __syncthreads();

  // cross-wave merge: thread t owns row (q2, l2); ties -> lowest col
  const int q2 = t >> 6, l2 = t & 63;
  float2 m = cand[0][q2][l2];
  float best = m.x; int bc = __float_as_int(m.y);
  #pragma unroll
  for (int w = 1; w < 4; ++w) {
    float2 c2 = cand[w][q2][l2];
    int k2 = __float_as_int(c2.y);
    if (c2.x < best || (c2.x == best && k2 < bc)) { best = c2.x; bc = k2; }
  }
  const int row = rowbase + q2 * 64 + l2;
  u64 key = ((u64)sortable_f32(best) << 32) | (unsigned)bc;
  atomicMin(&keys[(row << 2) | dict], key);
}

// ---- kernel 3: gather winners (coalesced via DT), write out + loss partials ----
__global__ __launch_bounds__(256, 8) void vq_merge(
    const float* __restrict__ x, const float* __restrict__ DT,
    const u64* __restrict__ keys,
    const float* __restrict__ alpha_p, const float* __restrict__ gamma_p,
    float* __restrict__ out, float* __restrict__ partials)
{
  __shared__ int kk[2][4];
  __shared__ float wr[4];
  const int t = threadIdx.x;
  const int c = t & 127, rs = t >> 7;
  const int row0 = blockIdx.x * 2;
  if (t < 8) {
    int r = t >> 2, d = t & 3;
    kk[r][d] = (int)(keys[((row0 + r) << 2) | d] & 0xFFFFFFFFull);
  }
  __syncthreads();
  const int row = row0 + rs;
  const float a = alpha_p[0];
  const float g0 = gamma_p[0], g1 = gamma_p[1], g2 = gamma_p[2], g3 = gamma_p[3];
  const float xv = x[(size_t)row * CDIM + c];
  const float d0 = DT[         kk[rs][0] * 128 + c];
  const float d1 = DT[ 8192  + kk[rs][1] * 128 + c];
  const float d2 = DT[ 24576 + kk[rs][2] * 128 + c];
  const float d3 = DT[ 57344 + kk[rs][3] * 128 + c];
  out[(size_t)row * CDIM + c] = a * (g0*d0 + g1*d1 + g2*d2 + g3*d3);
  float e0 = fmaf(-a, d0, xv), e1 = fmaf(-a, d1, xv);
  float e2 = fmaf(-a, d2, xv), e3 = fmaf(-a, d3, xv);
  float lc = g0*e0*e0 + g1*e1*e1 + g2*e2*e2 + g3*e3*e3;
  #pragma unroll
  for (int off = 32; off > 0; off >>= 1) lc += __shfl_down(lc, off);
  if ((t & 63) == 0) wr[t >> 6] = lc;
  __syncthreads();
  if (t == 0) partials[blockIdx.x] = wr[0] + wr[1] + wr[2] + wr[3];
}

// ---- kernel 4: final deterministic loss reduction ----
__global__ void vq_loss(const float* __restrict__ partials, float* __restrict__ lossp) {
  __shared__ float wr[4];
  const int t = threadIdx.x;
  float v = 0.f;
  #pragma unroll 8
  for (int i = 0; i < 128; ++i) v += partials[i * 256 + t];
  #pragma unroll
  for (int off = 32; off > 0; off >>= 1) v += __shfl_down(v, off);
  if ((t & 63) == 0) wr[t >> 6] = v;
  __syncthreads();
  if (t == 0) lossp[0] = (wr[0] + wr[1] + wr[2] + wr[3]) * (1.25f / 8388608.f);
}

extern "C" void kernel_launch(void* const* d_in, const int* in_sizes, int n_in,
                              void* d_out, int out_size, void* d_ws, size_t ws_size,
                              hipStream_t stream) {
  const float* x  = (const float*)d_in[0];
  const float* D0 = (const float*)d_in[1];
  const float* D1 = (const float*)d_in[2];
  const float* D2 = (const float*)d_in[3];
  const float* D3 = (const float*)d_in[4];
  const float* alpha = (const float*)d_in[5];
  const float* gamma = (const float*)d_in[6];
  float* out = (float*)d_out;

  float* ws = (float*)d_ws;
  float* nrm = ws;                       // 960
  float* DT  = ws + 1024;                // 122880
  u64*  keys = (u64*)(ws + 131072);      // 262144 u64
  float* partials = ws + 655360;         // 32768

  vq_prep<<<4, 256, 0, stream>>>(D0, D1, D2, D3, nrm, DT);
  vq_initkeys<<<256, 256, 0, stream>>>(keys);
  vq_tiles<<<3840, 256, 0, stream>>>(x, D0, D1, D2, D3, nrm, keys);
  vq_merge<<<32768, 256, 0, stream>>>(x, DT, keys, alpha, gamma, out, partials);
  vq_loss<<<1, 256, 0, stream>>>(partials, out + NC);
}

// Round 4
// 322.096 us; speedup vs baseline: 1.2607x; 1.2607x over previous
//
#include <hip/hip_runtime.h>

#define CDIM 128
#define NC   8388608

// ws layout (float offsets):
//   nrm      @ 0       (960)
//   DT       @ 1024    (122880: DT0@+0, DT1@+8192, DT2@+24576, DT3@+57344)
//   keys     @ 131072  (262144 ints)
//   partials @ 393216  (32768 floats)

// ---- kernel 0: column norms + transposed dict copies ----
__global__ void vq_prep(const float* __restrict__ D0, const float* __restrict__ D1,
                        const float* __restrict__ D2, const float* __restrict__ D3,
                        float* __restrict__ nrm, float* __restrict__ DT) {
  int g = blockIdx.x * 256 + threadIdx.x;
  if (g >= 960) return;
  const float* D; int K, k; float* T;
  if (g < 64)       { D = D0; K = 64;  k = g;       T = DT; }
  else if (g < 192) { D = D1; K = 128; k = g - 64;  T = DT + 8192; }
  else if (g < 448) { D = D2; K = 256; k = g - 192; T = DT + 24576; }
  else              { D = D3; K = 512; k = g - 448; T = DT + 57344; }
  float s = 0.f;
  for (int c = 0; c < 128; ++c) {
    float v = D[c * K + k];
    s = fmaf(v, v, s);
    T[k * 128 + c] = v;
  }
  nrm[g] = s;
}

// 32 explicit FMAs for one c-step: rows (a*, b*) x 16 cols. All named regs.
#define CSTEP(CC, XA_C, XB_C) { \
  const float* dr = Dp + (c4 * 4 + CC) * K; \
  float4 dv0 = *(const float4*)(dr); \
  float4 dv1 = *(const float4*)(dr + 4); \
  float4 dv2 = *(const float4*)(dr + 8); \
  float4 dv3 = *(const float4*)(dr + 12); \
  float xc0 = (XA_C), xc1 = (XB_C); \
  a0.x = fmaf(xc0, dv0.x, a0.x); a0.y = fmaf(xc0, dv0.y, a0.y); \
  a0.z = fmaf(xc0, dv0.z, a0.z); a0.w = fmaf(xc0, dv0.w, a0.w); \
  a1.x = fmaf(xc0, dv1.x, a1.x); a1.y = fmaf(xc0, dv1.y, a1.y); \
  a1.z = fmaf(xc0, dv1.z, a1.z); a1.w = fmaf(xc0, dv1.w, a1.w); \
  a2.x = fmaf(xc0, dv2.x, a2.x); a2.y = fmaf(xc0, dv2.y, a2.y); \
  a2.z = fmaf(xc0, dv2.z, a2.z); a2.w = fmaf(xc0, dv2.w, a2.w); \
  a3.x = fmaf(xc0, dv3.x, a3.x); a3.y = fmaf(xc0, dv3.y, a3.y); \
  a3.z = fmaf(xc0, dv3.z, a3.z); a3.w = fmaf(xc0, dv3.w, a3.w); \
  b0.x = fmaf(xc1, dv0.x, b0.x); b0.y = fmaf(xc1, dv0.y, b0.y); \
  b0.z = fmaf(xc1, dv0.z, b0.z); b0.w = fmaf(xc1, dv0.w, b0.w); \
  b1.x = fmaf(xc1, dv1.x, b1.x); b1.y = fmaf(xc1, dv1.y, b1.y); \
  b1.z = fmaf(xc1, dv1.z, b1.z); b1.w = fmaf(xc1, dv1.w, b1.w); \
  b2.x = fmaf(xc1, dv2.x, b2.x); b2.y = fmaf(xc1, dv2.y, b2.y); \
  b2.z = fmaf(xc1, dv2.z, b2.z); b2.w = fmaf(xc1, dv2.w, b2.w); \
  b3.x = fmaf(xc1, dv3.x, b3.x); b3.y = fmaf(xc1, dv3.y, b3.y); \
  b3.z = fmaf(xc1, dv3.z, b3.z); b3.w = fmaf(xc1, dv3.w, b3.w); }

#define UPD0(AV, NV, OFF) cr = fmaf(-2.f, (AV), (NV)); \
  if (cr < best0) { best0 = cr; bc0 = colbase + (OFF); }
#define UPD1(AV, NV, OFF) cr = fmaf(-2.f, (AV), (NV)); \
  if (cr < best1) { best1 = cr; bc1 = colbase + (OFF); }

template<int K>
__device__ __forceinline__ void scoreDict(
    const float* __restrict__ D, const float* __restrict__ nseg,
    const float4 (*__restrict__ xs)[33], const int l, const int wid,
    float& best0, int& bc0, float& best1, int& bc1)
{
  best0 = 1e30f; bc0 = 0; best1 = 1e30f; bc1 = 0;
  for (int tb = 0; tb < K; tb += 64) {
    const int colbase = __builtin_amdgcn_readfirstlane(tb + wid * 16);
    const float* __restrict__ Dp = D + colbase;
    float4 a0 = make_float4(0.f, 0.f, 0.f, 0.f);
    float4 a1 = a0, a2 = a0, a3 = a0;
    float4 b0 = a0, b1 = a0, b2 = a0, b3 = a0;
    #pragma unroll 2
    for (int c4 = 0; c4 < 32; ++c4) {
      float4 xa = xs[l][c4];
      float4 xb = xs[l + 64][c4];
      CSTEP(0, xa.x, xb.x)
      CSTEP(1, xa.y, xb.y)
      CSTEP(2, xa.z, xb.z)
      CSTEP(3, xa.w, xb.w)
    }
    const float* ns = nseg + colbase;
    float4 nv0 = *(const float4*)(ns);
    float4 nv1 = *(const float4*)(ns + 4);
    float4 nv2 = *(const float4*)(ns + 8);
    float4 nv3 = *(const float4*)(ns + 12);
    float cr;
    UPD0(a0.x, nv0.x, 0)  UPD0(a0.y, nv0.y, 1)  UPD0(a0.z, nv0.z, 2)  UPD0(a0.w, nv0.w, 3)
    UPD0(a1.x, nv1.x, 4)  UPD0(a1.y, nv1.y, 5)  UPD0(a1.z, nv1.z, 6)  UPD0(a1.w, nv1.w, 7)
    UPD0(a2.x, nv2.x, 8)  UPD0(a2.y, nv2.y, 9)  UPD0(a2.z, nv2.z, 10) UPD0(a2.w, nv2.w, 11)
    UPD0(a3.x, nv3.x, 12) UPD0(a3.y, nv3.y, 13) UPD0(a3.z, nv3.z, 14) UPD0(a3.w, nv3.w, 15)
    UPD1(b0.x, nv0.x, 0)  UPD1(b0.y, nv0.y, 1)  UPD1(b0.z, nv0.z, 2)  UPD1(b0.w, nv0.w, 3)
    UPD1(b1.x, nv1.x, 4)  UPD1(b1.y, nv1.y, 5)  UPD1(b1.z, nv1.z, 6)  UPD1(b1.w, nv1.w, 7)
    UPD1(b2.x, nv2.x, 8)  UPD1(b2.y, nv2.y, 9)  UPD1(b2.z, nv2.z, 10) UPD1(b2.w, nv2.w, 11)
    UPD1(b3.x, nv3.x, 12) UPD1(b3.y, nv3.y, 13) UPD1(b3.z, nv3.z, 14) UPD1(b3.w, nv3.w, 15)
  }
}

// ---- kernel 1: score all dicts for 128 rows/block; write winning cols ----
__global__ __launch_bounds__(256, 2) void vq_main(
    const float* __restrict__ x,
    const float* __restrict__ D0, const float* __restrict__ D1,
    const float* __restrict__ D2, const float* __restrict__ D3,
    const float* __restrict__ nrm, int* __restrict__ keys)
{
  __shared__ float4 xs[128][33];      // 66 KB, padded: b128 reads/writes tile all banks
  __shared__ float2 cand[4][2][64];   // [wave][rowq][lane] : (crit, col)

  const int t = threadIdx.x;
  const int l = t & 63;
  const int wid = t >> 6;

  // stage x slab (128 rows) into LDS, transpose-free, coalesced global reads
  const float4* __restrict__ xg = (const float4*)x + (size_t)blockIdx.x * 4096;
  #pragma unroll
  for (int j = 0; j < 16; ++j) {
    int f = j * 256 + t;
    xs[f >> 5][f & 31] = xg[f];
  }
  __syncthreads();

  float best0, best1; int bc0, bc1;
  const int rowg = (blockIdx.x * 128 + t) << 2;   // key base for merge thread t

  scoreDict< 64>(D0, nrm +   0, xs, l, wid, best0, bc0, best1, bc1);
  cand[wid][0][l] = make_float2(best0, __int_as_float(bc0));
  cand[wid][1][l] = make_float2(best1, __int_as_float(bc1));
  __syncthreads();
  if (t < 128) {
    int q = t >> 6, ll = t & 63;
    float2 m = cand[0][q][ll]; float mb = m.x; int mk = __float_as_int(m.y);
    #pragma unroll
    for (int w = 1; w < 4; ++w) {
      float2 c2 = cand[w][q][ll]; int k2 = __float_as_int(c2.y);
      if (c2.x < mb || (c2.x == mb && k2 < mk)) { mb = c2.x; mk = k2; }
    }
    keys[rowg | 0] = mk;
  }
  __syncthreads();

  scoreDict<128>(D1, nrm +  64, xs, l, wid, best0, bc0, best1, bc1);
  cand[wid][0][l] = make_float2(best0, __int_as_float(bc0));
  cand[wid][1][l] = make_float2(best1, __int_as_float(bc1));
  __syncthreads();
  if (t < 128) {
    int q = t >> 6, ll = t & 63;
    float2 m = cand[0][q][ll]; float mb = m.x; int mk = __float_as_int(m.y);
    #pragma unroll
    for (int w = 1; w < 4; ++w) {
      float2 c2 = cand[w][q][ll]; int k2 = __float_as_int(c2.y);
      if (c2.x < mb || (c2.x == mb && k2 < mk)) { mb = c2.x; mk = k2; }
    }
    keys[rowg | 1] = mk;
  }
  __syncthreads();

  scoreDict<256>(D2, nrm + 192, xs, l, wid, best0, bc0, best1, bc1);
  cand[wid][0][l] = make_float2(best0, __int_as_float(bc0));
  cand[wid][1][l] = make_float2(best1, __int_as_float(bc1));
  __syncthreads();
  if (t < 128) {
    int q = t >> 6, ll = t & 63;
    float2 m = cand[0][q][ll]; float mb = m.x; int mk = __float_as_int(m.y);
    #pragma unroll
    for (int w = 1; w < 4; ++w) {
      float2 c2 = cand[w][q][ll]; int k2 = __float_as_int(c2.y);
      if (c2.x < mb || (c2.x == mb && k2 < mk)) { mb = c2.x; mk = k2; }
    }
    keys[rowg | 2] = mk;
  }
  __syncthreads();

  scoreDict<512>(D3, nrm + 448, xs, l, wid, best0, bc0, best1, bc1);
  cand[wid][0][l] = make_float2(best0, __int_as_float(bc0));
  cand[wid][1][l] = make_float2(best1, __int_as_float(bc1));
  __syncthreads();
  if (t < 128) {
    int q = t >> 6, ll = t & 63;
    float2 m = cand[0][q][ll]; float mb = m.x; int mk = __float_as_int(m.y);
    #pragma unroll
    for (int w = 1; w < 4; ++w) {
      float2 c2 = cand[w][q][ll]; int k2 = __float_as_int(c2.y);
      if (c2.x < mb || (c2.x == mb && k2 < mk)) { mb = c2.x; mk = k2; }
    }
    keys[rowg | 3] = mk;
  }
}

// ---- kernel 2: gather winners (coalesced via DT), write out + loss partials ----
__global__ __launch_bounds__(256, 8) void vq_merge(
    const float* __restrict__ x, const float* __restrict__ DT,
    const int* __restrict__ keys,
    const float* __restrict__ alpha_p, const float* __restrict__ gamma_p,
    float* __restrict__ out, float* __restrict__ partials)
{
  __shared__ int kk[2][4];
  __shared__ float wr[4];
  const int t = threadIdx.x;
  const int c = t & 127, rs = t >> 7;
  const int row0 = blockIdx.x * 2;
  if (t < 8) {
    int r = t >> 2, d = t & 3;
    kk[r][d] = keys[((row0 + r) << 2) | d];
  }
  __syncthreads();
  const int row = row0 + rs;
  const float a = alpha_p[0];
  const float g0 = gamma_p[0], g1 = gamma_p[1], g2 = gamma_p[2], g3 = gamma_p[3];
  const float xv = x[(size_t)row * CDIM + c];
  const float d0 = DT[         kk[rs][0] * 128 + c];
  const float d1 = DT[ 8192  + kk[rs][1] * 128 + c];
  const float d2 = DT[ 24576 + kk[rs][2] * 128 + c];
  const float d3 = DT[ 57344 + kk[rs][3] * 128 + c];
  out[(size_t)row * CDIM + c] = a * (g0*d0 + g1*d1 + g2*d2 + g3*d3);
  float e0 = fmaf(-a, d0, xv), e1 = fmaf(-a, d1, xv);
  float e2 = fmaf(-a, d2, xv), e3 = fmaf(-a, d3, xv);
  float lc = g0*e0*e0 + g1*e1*e1 + g2*e2*e2 + g3*e3*e3;
  #pragma unroll
  for (int off = 32; off > 0; off >>= 1) lc += __shfl_down(lc, off);
  if ((t & 63) == 0) wr[t >> 6] = lc;
  __syncthreads();
  if (t == 0) partials[blockIdx.x] = wr[0] + wr[1] + wr[2] + wr[3];
}

// ---- kernel 3: final deterministic loss reduction ----
__global__ void vq_loss(const float* __restrict__ partials, float* __restrict__ lossp) {
  __shared__ float wr[4];
  const int t = threadIdx.x;
  float v = 0.f;
  #pragma unroll 8
  for (int i = 0; i < 128; ++i) v += partials[i * 256 + t];
  #pragma unroll
  for (int off = 32; off > 0; off >>= 1) v += __shfl_down(v, off);
  if ((t & 63) == 0) wr[t >> 6] = v;
  __syncthreads();
  if (t == 0) lossp[0] = (wr[0] + wr[1] + wr[2] + wr[3]) * (1.25f / 8388608.f);
}

extern "C" void kernel_launch(void* const* d_in, const int* in_sizes, int n_in,
                              void* d_out, int out_size, void* d_ws, size_t ws_size,
                              hipStream_t stream) {
  const float* x  = (const float*)d_in[0];
  const float* D0 = (const float*)d_in[1];
  const float* D1 = (const float*)d_in[2];
  const float* D2 = (const float*)d_in[3];
  const float* D3 = (const float*)d_in[4];
  const float* alpha = (const float*)d_in[5];
  const float* gamma = (const float*)d_in[6];
  float* out = (float*)d_out;

  float* ws = (float*)d_ws;
  float* nrm = ws;                        // 960
  float* DT  = ws + 1024;                 // 122880
  int*  keys = (int*)(ws + 131072);       // 262144 ints
  float* partials = ws + 393216;          // 32768

  vq_prep<<<4, 256, 0, stream>>>(D0, D1, D2, D3, nrm, DT);
  vq_main<<<512, 256, 0, stream>>>(x, D0, D1, D2, D3, nrm, keys);
  vq_merge<<<32768, 256, 0, stream>>>(x, DT, keys, alpha, gamma, out, partials);
  vq_loss<<<1, 256, 0, stream>>>(partials, out + NC);
}